// Round 1
// baseline (1178.919 us; speedup 1.0000x reference)
//
#include <hip/hip_runtime.h>
#include <hip/hip_bf16.h>

typedef __attribute__((ext_vector_type(8))) short short8;
typedef __attribute__((ext_vector_type(4))) float f32x4;

#define NSAMP 50
#define MTOT 204800   // B*S*NS
#define BS_TOT 4096   // B*S

__device__ __forceinline__ unsigned short f2bf(float f) {
  unsigned int u = __builtin_bit_cast(unsigned int, f);
  u += 0x7fffu + ((u >> 16) & 1u);   // RNE
  return (unsigned short)(u >> 16);
}

__device__ __forceinline__ float softplusf(float x) {
  return fmaxf(x, 0.f) + log1pf(__expf(-fabsf(x)));
}

// ---------------- K0: w_noise -> bf16 ; w_in -> transposed [h][o] ----------
__global__ __launch_bounds__(256) void k0_prep(const float* __restrict__ w_in,
    const float* __restrict__ w_noise, float* __restrict__ w_in_t,
    unsigned short* __restrict__ wn_bf) {
  int r = blockIdx.x;            // 512 rows
  int t = threadIdx.x;
#pragma unroll
  for (int q = 0; q < 2; ++q) {
    int col = t + 256 * q;
    wn_bf[r * 512 + col] = f2bf(w_noise[r * 512 + col]);
    w_in_t[col * 512 + r] = w_in[r * 512 + col];   // w_in_t[h][o] = w_in[o][h]
  }
}

// ---------------- K1: embeddings + per-event dot products ------------------
// hv[bs][0:256]=pe, hv[bs][256:512]=temb ; ab[0..3][bs] = a_s,b_s,a_g,b_g
__global__ __launch_bounds__(256) void k1_embed(const int* __restrict__ etype,
    const float* __restrict__ etime, const float* __restrict__ wt,
    const float* __restrict__ table, const float* __restrict__ w_sigma,
    const float* __restrict__ w_gate, float* __restrict__ hv,
    float* __restrict__ ab) {
  int bs = blockIdx.x;           // 4096
  int d = threadIdx.x;           // 256
  int s = bs & 1023;
  int ty = etype[bs];
  float te = table[ty * 256 + d];
  float t = etime[bs];
  int k = d & 127;
  float div_term = __expf((float)(2 * k) * (-9.210340371976184f / 256.f));
  float arg = (float)s * div_term + t * wt[k];
  float pe = (d < 128) ? sinf(arg) : cosf(arg);
  hv[(size_t)bs * 512 + d] = pe;
  hv[(size_t)bs * 512 + 256 + d] = te;
  float p0 = te * w_sigma[d];
  float p1 = te * w_sigma[256 + d];
  float p2 = te * w_gate[d];
  float p3 = te * w_gate[256 + d];
#pragma unroll
  for (int m = 1; m < 64; m <<= 1) {
    p0 += __shfl_xor(p0, m, 64);
    p1 += __shfl_xor(p1, m, 64);
    p2 += __shfl_xor(p2, m, 64);
    p3 += __shfl_xor(p3, m, 64);
  }
  __shared__ float red[4][4];
  if ((d & 63) == 0) {
    red[d >> 6][0] = p0; red[d >> 6][1] = p1;
    red[d >> 6][2] = p2; red[d >> 6][3] = p3;
  }
  __syncthreads();
  if (d < 4) ab[d * BS_TOT + bs] = red[0][d] + red[1][d] + red[2][d] + red[3][d];
}

// ---------------- K2: scores + aggregation + LN + mark_probs + c -----------
// Block = (b, tile-pair). Each block does tiles `pair` and `127-pair` (8 rows
// each) so total work per block is uniform (causal triangle balance).
__global__ __launch_bounds__(256) void k2_ctx(const float* __restrict__ etime,
    const float* __restrict__ hv, const float* __restrict__ ab,
    const float* __restrict__ ln_g, const float* __restrict__ ln_b,
    const float* __restrict__ w_pred, const float* __restrict__ w_in_t,
    float* __restrict__ cbuf, float* __restrict__ out) {
  __shared__ float sc_t[64][8];     // scores, [j][i] so b128 broadcast works
  __shared__ float sh_t[512][8];    // normalized hidden, [h][i]
  __shared__ float ti[8], bsi[8], bgi[8];
  __shared__ float red[4][8];
  __shared__ float lg[8][20];
  int tid = threadIdx.x;
  int b = blockIdx.x >> 6;          // 4
  int pair = blockIdx.x & 63;       // 64
  int jl = tid & 63;
  int ilb = tid >> 6;
  const float* et_b = etime + b * 1024;
  const float* as_b = ab + 0 * BS_TOT + b * 1024;
  const float* bs_b = ab + 1 * BS_TOT + b * 1024;
  const float* ag_b = ab + 2 * BS_TOT + b * 1024;
  const float* bg_b = ab + 3 * BS_TOT + b * 1024;

  for (int half = 0; half < 2; ++half) {
    int tile = half ? (127 - pair) : pair;
    int i0 = tile * 8;
    if (tid < 8) {
      ti[tid] = et_b[i0 + tid];
      bsi[tid] = bs_b[i0 + tid];
      bgi[tid] = bg_b[i0 + tid];
    }
    __syncthreads();
    float acc0[8], acc1[8];
#pragma unroll
    for (int il = 0; il < 8; ++il) { acc0[il] = 0.f; acc1[il] = 0.f; }
    for (int j0 = 0; j0 < i0 + 8; j0 += 64) {
      int j = j0 + jl;
      float as_j = as_b[j], ag_j = ag_b[j], tj = et_b[j];
#pragma unroll
      for (int q = 0; q < 2; ++q) {
        int il = ilb + 4 * q;
        int i = i0 + il;
        float sc = 0.f;
        if (j < i) {
          float sp = softplusf(as_j + bsi[il]);
          float g = 1.f / (1.f + __expf(-(ag_j + bgi[il])));
          sc = g * __expf(-sp * fabsf(tj - ti[il]));
        }
        sc_t[jl][il] = sc;
      }
      __syncthreads();
      const float* hvb = hv + ((size_t)(b * 1024 + j0)) * 512 + tid;
#pragma unroll 4
      for (int jj = 0; jj < 64; ++jj) {
        float h0 = hvb[jj * 512];
        float h1 = hvb[jj * 512 + 256];
        float4 s0 = *(const float4*)&sc_t[jj][0];
        float4 s1 = *(const float4*)&sc_t[jj][4];
        acc0[0] += s0.x * h0; acc1[0] += s0.x * h1;
        acc0[1] += s0.y * h0; acc1[1] += s0.y * h1;
        acc0[2] += s0.z * h0; acc1[2] += s0.z * h1;
        acc0[3] += s0.w * h0; acc1[3] += s0.w * h1;
        acc0[4] += s1.x * h0; acc1[4] += s1.x * h1;
        acc0[5] += s1.y * h0; acc1[5] += s1.y * h1;
        acc0[6] += s1.z * h0; acc1[6] += s1.z * h1;
        acc0[7] += s1.w * h0; acc1[7] += s1.w * h1;
      }
      __syncthreads();
    }
    // ---- LayerNorm (two-pass, matches reference) ----
#pragma unroll
    for (int il = 0; il < 8; ++il) {
      float sm = acc0[il] + acc1[il];
#pragma unroll
      for (int m = 1; m < 64; m <<= 1) sm += __shfl_xor(sm, m, 64);
      if (jl == 0) red[tid >> 6][il] = sm;
    }
    __syncthreads();
    float mean[8];
#pragma unroll
    for (int il = 0; il < 8; ++il)
      mean[il] = (red[0][il] + red[1][il] + red[2][il] + red[3][il]) * (1.f / 512.f);
    __syncthreads();
#pragma unroll
    for (int il = 0; il < 8; ++il) {
      float d0 = acc0[il] - mean[il], d1 = acc1[il] - mean[il];
      float sm = d0 * d0 + d1 * d1;
#pragma unroll
      for (int m = 1; m < 64; m <<= 1) sm += __shfl_xor(sm, m, 64);
      if (jl == 0) red[tid >> 6][il] = sm;
    }
    __syncthreads();
    float g0 = ln_g[tid], be0 = ln_b[tid];
    float g1 = ln_g[256 + tid], be1 = ln_b[256 + tid];
#pragma unroll
    for (int il = 0; il < 8; ++il) {
      float var = (red[0][il] + red[1][il] + red[2][il] + red[3][il]) * (1.f / 512.f);
      float rs = rsqrtf(var + 1e-6f);
      sh_t[tid][il] = (acc0[il] - mean[il]) * rs * g0 + be0;
      sh_t[256 + tid][il] = (acc1[il] - mean[il]) * rs * g1 + be1;
    }
    __syncthreads();
    // ---- mark logits + softmax ----
    if (tid < 160) {
      int il = tid / 20, p = tid - il * 20;
      const float* wp = w_pred + p * 512;
      float sum = 0.f;
#pragma unroll 4
      for (int h = 0; h < 512; ++h) sum += sh_t[h][il] * wp[h];
      lg[il][p] = sum;
    }
    __syncthreads();
    if (tid < 8) {
      float mx = -1e30f;
#pragma unroll
      for (int p = 0; p < 20; ++p) mx = fmaxf(mx, lg[tid][p]);
      float e[20], sum = 0.f;
#pragma unroll
      for (int p = 0; p < 20; ++p) { e[p] = __expf(lg[tid][p] - mx); sum += e[p]; }
      float inv = 1.f / sum;
      float* o = out + 4096 + ((size_t)(b * 1024 + i0 + tid)) * 20;
#pragma unroll
      for (int p = 0; p < 20; ++p) o[p] = e[p] * inv;
    }
    // ---- c = hidden_n @ w_in^T ----
    float cc0[8], cc1[8];
#pragma unroll
    for (int il = 0; il < 8; ++il) { cc0[il] = 0.f; cc1[il] = 0.f; }
#pragma unroll 8
    for (int h = 0; h < 512; ++h) {
      float w0 = w_in_t[h * 512 + tid];
      float w1 = w_in_t[h * 512 + 256 + tid];
      float4 h0 = *(const float4*)&sh_t[h][0];
      float4 h1 = *(const float4*)&sh_t[h][4];
      cc0[0] += h0.x * w0; cc1[0] += h0.x * w1;
      cc0[1] += h0.y * w0; cc1[1] += h0.y * w1;
      cc0[2] += h0.z * w0; cc1[2] += h0.z * w1;
      cc0[3] += h0.w * w0; cc1[3] += h0.w * w1;
      cc0[4] += h1.x * w0; cc1[4] += h1.x * w1;
      cc0[5] += h1.y * w0; cc1[5] += h1.y * w1;
      cc0[6] += h1.z * w0; cc1[6] += h1.z * w1;
      cc0[7] += h1.w * w0; cc1[7] += h1.w * w1;
    }
#pragma unroll
    for (int il = 0; il < 8; ++il) {
      float* cp = cbuf + ((size_t)(b * 1024 + i0 + il)) * 512;
      cp[tid] = cc0[il];
      cp[256 + tid] = cc1[il];
    }
    __syncthreads();
  }
}

// ---------------- K4: bf16 MFMA GEMM h=relu(noise@w_noise^T + c), ----------
// fused partial reduction  v_part[nt][m] = sum_{o in n-tile} relu(h)*w_time[o]
__global__ __launch_bounds__(256) void k4_gemm(const float* __restrict__ noise,
    const unsigned short* __restrict__ wn_bf, const float* __restrict__ cbuf,
    const float* __restrict__ w_time, float* __restrict__ v_part) {
  __shared__ unsigned short As[128][32];   // bf16 A tile (rows m, k-contig)
  __shared__ unsigned short Bs[128][32];   // bf16 B tile (rows n, k-contig)
  __shared__ float v_s[128];
  int tid = threadIdx.x;
  int nt = blockIdx.x & 3;       // n-tile (interleaved for L3 reuse of noise)
  int mt = blockIdx.x >> 2;      // 1600 m-tiles
  size_t m0 = (size_t)mt * 128;
  int n0 = nt * 128;
  int lane = tid & 63, wv = tid >> 6;
  int wm = wv >> 1, wn = wv & 1;
  int quad = lane >> 4, lcol = lane & 15;
  f32x4 acc[4][4] = {};

  for (int kt = 0; kt < 512; kt += 32) {
    __syncthreads();
    // stage A: 128x32 fp32 -> bf16
#pragma unroll
    for (int q = 0; q < 4; ++q) {
      int c = tid + 256 * q;
      int row = c >> 3;
      int kq = (c & 7) << 2;
      float4 f = *(const float4*)(noise + ((m0 + row) << 9) + kt + kq);
      ushort4 u;
      u.x = f2bf(f.x); u.y = f2bf(f.y); u.z = f2bf(f.z); u.w = f2bf(f.w);
      *(ushort4*)&As[row][kq] = u;
    }
    // stage B: 128x32 bf16 (pre-converted)
#pragma unroll
    for (int q = 0; q < 2; ++q) {
      int c = tid + 256 * q;
      int row = c >> 2;
      int kq = (c & 3) << 3;
      *(uint4*)&Bs[row][kq] =
          *(const uint4*)(wn_bf + ((size_t)(n0 + row) << 9) + kt + kq);
    }
    __syncthreads();
    short8 af[4], bfr[4];
#pragma unroll
    for (int i = 0; i < 4; ++i)
      af[i] = *(const short8*)&As[wm * 64 + i * 16 + lcol][quad * 8];
#pragma unroll
    for (int j = 0; j < 4; ++j)
      bfr[j] = *(const short8*)&Bs[wn * 64 + j * 16 + lcol][quad * 8];
#pragma unroll
    for (int i = 0; i < 4; ++i)
#pragma unroll
      for (int j = 0; j < 4; ++j)
        acc[i][j] = __builtin_amdgcn_mfma_f32_16x16x32_bf16(af[i], bfr[j],
                                                            acc[i][j], 0, 0, 0);
  }
  __syncthreads();
  if (tid < 128) v_s[tid] = 0.f;
  __syncthreads();
  // epilogue: +c, relu, weighted row-sum over this 128-col slab
  float rowsum[4][4];
#pragma unroll
  for (int i = 0; i < 4; ++i)
#pragma unroll
    for (int r = 0; r < 4; ++r) rowsum[i][r] = 0.f;
#pragma unroll
  for (int i = 0; i < 4; ++i) {
    int rowb = wm * 64 + i * 16 + quad * 4;
#pragma unroll
    for (int j = 0; j < 4; ++j) {
      int col = n0 + wn * 64 + j * 16 + lcol;
      float wtv = w_time[col];
#pragma unroll
      for (int r = 0; r < 4; ++r) {
        int grow = (int)m0 + rowb + r;
        int bs = grow / NSAMP;
        float hval = acc[i][j][r] + cbuf[((size_t)bs << 9) + col];
        rowsum[i][r] += fmaxf(hval, 0.f) * wtv;
      }
    }
  }
#pragma unroll
  for (int i = 0; i < 4; ++i)
#pragma unroll
    for (int r = 0; r < 4; ++r) {
      float v = rowsum[i][r];
      v += __shfl_xor(v, 1, 64);
      v += __shfl_xor(v, 2, 64);
      v += __shfl_xor(v, 4, 64);
      v += __shfl_xor(v, 8, 64);
      if (lcol == 0) atomicAdd(&v_s[wm * 64 + i * 16 + quad * 4 + r], v);
    }
  __syncthreads();
  if (tid < 128) v_part[(size_t)nt * MTOT + m0 + tid] = v_s[tid];
}

// ---------------- K5: pred_time = mean_n softplus(sum of partials) ---------
__global__ __launch_bounds__(64) void k5_pred(const float* __restrict__ v_part,
                                              float* __restrict__ out) {
  int bs = blockIdx.x;
  int t = threadIdx.x;
  float sp = 0.f;
  if (t < NSAMP) {
    size_t idx = (size_t)bs * NSAMP + t;
    float v = v_part[idx] + v_part[(size_t)MTOT + idx] +
              v_part[2 * (size_t)MTOT + idx] + v_part[3 * (size_t)MTOT + idx];
    sp = softplusf(v);
  }
#pragma unroll
  for (int m = 1; m < 64; m <<= 1) sp += __shfl_xor(sp, m, 64);
  if (t == 0) out[bs] = sp * (1.f / NSAMP);
}

extern "C" void kernel_launch(void* const* d_in, const int* in_sizes, int n_in,
                              void* d_out, int out_size, void* d_ws, size_t ws_size,
                              hipStream_t stream) {
  const int* etype    = (const int*)d_in[0];
  const float* etime  = (const float*)d_in[1];
  const float* noise  = (const float*)d_in[2];
  const float* wt     = (const float*)d_in[3];
  const float* table  = (const float*)d_in[4];
  const float* w_sigma= (const float*)d_in[5];
  const float* w_gate = (const float*)d_in[6];
  const float* ln_g   = (const float*)d_in[7];
  const float* ln_b   = (const float*)d_in[8];
  const float* w_pred = (const float*)d_in[9];
  const float* w_in   = (const float*)d_in[10];
  const float* w_noise= (const float*)d_in[11];
  const float* w_time = (const float*)d_in[12];
  float* out = (float*)d_out;
  char* ws = (char*)d_ws;
  // workspace layout (21.7 MB total)
  float* hv             = (float*)(ws);                    // 8 MB  [B*S][512]
  float* ab             = (float*)(ws + 8388608);          // 64 KB [4][B*S]
  float* cbuf           = (float*)(ws + 8454144);          // 8 MB  [B*S][512]
  unsigned short* wn_bf = (unsigned short*)(ws + 16842752);// 512 KB
  float* w_in_t         = (float*)(ws + 17367040);         // 1 MB
  float* v_part         = (float*)(ws + 18415616);         // 3.2 MB [4][MTOT]

  hipLaunchKernelGGL(k0_prep, dim3(512), dim3(256), 0, stream,
                     w_in, w_noise, w_in_t, wn_bf);
  hipLaunchKernelGGL(k1_embed, dim3(4096), dim3(256), 0, stream,
                     etype, etime, wt, table, w_sigma, w_gate, hv, ab);
  hipLaunchKernelGGL(k2_ctx, dim3(256), dim3(256), 0, stream,
                     etime, hv, ab, ln_g, ln_b, w_pred, w_in_t, cbuf, out);
  hipLaunchKernelGGL(k4_gemm, dim3(6400), dim3(256), 0, stream,
                     noise, wn_bf, cbuf, w_time, v_part);
  hipLaunchKernelGGL(k5_pred, dim3(4096), dim3(64), 0, stream, v_part, out);
}

// Round 2
// 837.526 us; speedup vs baseline: 1.4076x; 1.4076x over previous
//
#include <hip/hip_runtime.h>
#include <hip/hip_bf16.h>

typedef __attribute__((ext_vector_type(8))) short short8;
typedef __attribute__((ext_vector_type(4))) float f32x4;

#define NSAMP 50
#define MTOT 204800   // B*S*NS
#define BS_TOT 4096   // B*S

__device__ __forceinline__ unsigned short f2bf(float f) {
  unsigned int u = __builtin_bit_cast(unsigned int, f);
  u += 0x7fffu + ((u >> 16) & 1u);   // RNE
  return (unsigned short)(u >> 16);
}

// pack trunc(a),trunc(b) -> dword in ONE v_perm_b32 (bytes a2,a3,b2,b3)
__device__ __forceinline__ unsigned int pk_bf_trunc(float a, float b) {
  return __builtin_amdgcn_perm(__builtin_bit_cast(unsigned int, b),
                               __builtin_bit_cast(unsigned int, a), 0x07060302u);
}

__device__ __forceinline__ float softplusf(float x) {
  return fmaxf(x, 0.f) + log1pf(__expf(-fabsf(x)));
}

// ---------------- K0: w_noise -> bf16 --------------------------------------
__global__ __launch_bounds__(256) void k0_prep(const float* __restrict__ w_noise,
                                               unsigned short* __restrict__ wn_bf) {
  int r = blockIdx.x;            // 512 rows
  int t = threadIdx.x;
#pragma unroll
  for (int q = 0; q < 2; ++q) {
    int col = t + 256 * q;
    wn_bf[r * 512 + col] = f2bf(w_noise[r * 512 + col]);
  }
}

// ---------------- K1: embeddings + per-event dot products ------------------
__global__ __launch_bounds__(256) void k1_embed(const int* __restrict__ etype,
    const float* __restrict__ etime, const float* __restrict__ wt,
    const float* __restrict__ table, const float* __restrict__ w_sigma,
    const float* __restrict__ w_gate, float* __restrict__ hv,
    float* __restrict__ ab) {
  int bs = blockIdx.x;           // 4096
  int d = threadIdx.x;           // 256
  int s = bs & 1023;
  int ty = etype[bs];
  float te = table[ty * 256 + d];
  float t = etime[bs];
  int k = d & 127;
  float div_term = __expf((float)(2 * k) * (-9.210340371976184f / 256.f));
  float arg = (float)s * div_term + t * wt[k];
  float pe = (d < 128) ? sinf(arg) : cosf(arg);
  hv[(size_t)bs * 512 + d] = pe;
  hv[(size_t)bs * 512 + 256 + d] = te;
  float p0 = te * w_sigma[d];
  float p1 = te * w_sigma[256 + d];
  float p2 = te * w_gate[d];
  float p3 = te * w_gate[256 + d];
#pragma unroll
  for (int m = 1; m < 64; m <<= 1) {
    p0 += __shfl_xor(p0, m, 64);
    p1 += __shfl_xor(p1, m, 64);
    p2 += __shfl_xor(p2, m, 64);
    p3 += __shfl_xor(p3, m, 64);
  }
  __shared__ float red[4][4];
  if ((d & 63) == 0) {
    red[d >> 6][0] = p0; red[d >> 6][1] = p1;
    red[d >> 6][2] = p2; red[d >> 6][3] = p3;
  }
  __syncthreads();
  if (d < 4) ab[d * BS_TOT + bs] = red[0][d] + red[1][d] + red[2][d] + red[3][d];
}

// ---------------- K1t: hv[bs][512] -> hvT_bf[b][h][s] (bf16 transpose) -----
__global__ __launch_bounds__(256) void k1t_transpose(const float* __restrict__ hv,
                                                     unsigned short* __restrict__ hvT) {
  __shared__ float T[64][65];
  int bid = blockIdx.x;          // 4 * 16 * 8 = 512
  int b = bid >> 7;
  int st = (bid & 127) >> 3;
  int ht = bid & 7;
  int s0 = st * 64, h0 = ht * 64;
  int t = threadIdx.x;
#pragma unroll
  for (int q = 0; q < 16; ++q) {
    int idx = t + 256 * q;
    int r = idx >> 6, c = idx & 63;
    T[c][r] = hv[((size_t)(b * 1024 + s0 + r)) * 512 + h0 + c];
  }
  __syncthreads();
  int sq = t & 15;
#pragma unroll
  for (int q = 0; q < 4; ++q) {
    int hh = (t >> 4) + 16 * q;
    ushort4 u;
    u.x = f2bf(T[hh][sq * 4 + 0]);
    u.y = f2bf(T[hh][sq * 4 + 1]);
    u.z = f2bf(T[hh][sq * 4 + 2]);
    u.w = f2bf(T[hh][sq * 4 + 3]);
    *(ushort4*)(hvT + ((size_t)b << 19) + ((size_t)(h0 + hh) << 10) + s0 + sq * 4) = u;
  }
}

// ---------------- K2a: scores -> bf16 [b][i][j], zero for j>=i -------------
__global__ __launch_bounds__(256) void k2a_scores(const float* __restrict__ etime,
    const float* __restrict__ ab, unsigned short* __restrict__ S) {
  __shared__ float ti[8], bsi[8], bgi[8];
  int bid = blockIdx.x;          // 4 * 128 = 512
  int b = bid >> 7;
  int i0 = (bid & 127) * 8;
  int t = threadIdx.x;
  const float* et_b = etime + b * 1024;
  const float* as_b = ab + 0 * BS_TOT + b * 1024;
  const float* bs_b = ab + 1 * BS_TOT + b * 1024;
  const float* ag_b = ab + 2 * BS_TOT + b * 1024;
  const float* bg_b = ab + 3 * BS_TOT + b * 1024;
  if (t < 8) {
    ti[t] = et_b[i0 + t];
    bsi[t] = bs_b[i0 + t];
    bgi[t] = bg_b[i0 + t];
  }
  __syncthreads();
  unsigned short* Sb = S + ((size_t)b << 20);
  for (int j0 = 0; j0 < 1024; j0 += 256) {
    int j = j0 + t;
    float as_j = as_b[j], ag_j = ag_b[j], tj = et_b[j];
#pragma unroll
    for (int il = 0; il < 8; ++il) {
      int i = i0 + il;
      float sc = 0.f;
      if (j < i) {
        float sp = softplusf(as_j + bsi[il]);
        float g = 1.f / (1.f + __expf(-(ag_j + bgi[il])));
        sc = g * __expf(-sp * fabsf(tj - ti[il]));
      }
      Sb[((size_t)i << 10) + j] = f2bf(sc);
    }
  }
}

// ---------------- K2b: hidden = S @ hv  (bf16 MFMA, causal k-stop) ---------
__global__ __launch_bounds__(256) void k2b_agg(const unsigned short* __restrict__ S,
    const unsigned short* __restrict__ hvT, float* __restrict__ hidden) {
  __shared__ unsigned short As[128][32];
  __shared__ unsigned short Bs[128][32];
  int bid = blockIdx.x;          // 4b * 8mt * 4nt = 128
  int b = bid >> 5;
  int mt = (bid >> 2) & 7;
  int nt = bid & 3;
  int i0 = mt * 128, n0 = nt * 128;
  int kmax = i0 + 128;
  int tid = threadIdx.x;
  int lane = tid & 63, wv = tid >> 6;
  int wm = wv >> 1, wn = wv & 1;
  int quad = lane >> 4, lcol = lane & 15;
  const unsigned short* Sb = S + ((size_t)b << 20);
  const unsigned short* Hb = hvT + ((size_t)b << 19);
  f32x4 acc[4][4] = {};
  for (int kt = 0; kt < kmax; kt += 32) {
    __syncthreads();
#pragma unroll
    for (int q = 0; q < 2; ++q) {
      int c = tid + 256 * q;
      int row = c >> 2, kq = (c & 3) << 3;
      *(uint4*)&As[row][kq] = *(const uint4*)(Sb + (((size_t)(i0 + row)) << 10) + kt + kq);
      *(uint4*)&Bs[row][kq] = *(const uint4*)(Hb + (((size_t)(n0 + row)) << 10) + kt + kq);
    }
    __syncthreads();
    short8 af[4], bfr[4];
#pragma unroll
    for (int i = 0; i < 4; ++i)
      af[i] = *(const short8*)&As[wm * 64 + i * 16 + lcol][quad * 8];
#pragma unroll
    for (int j = 0; j < 4; ++j)
      bfr[j] = *(const short8*)&Bs[wn * 64 + j * 16 + lcol][quad * 8];
#pragma unroll
    for (int i = 0; i < 4; ++i)
#pragma unroll
      for (int j = 0; j < 4; ++j)
        acc[i][j] = __builtin_amdgcn_mfma_f32_16x16x32_bf16(af[i], bfr[j],
                                                            acc[i][j], 0, 0, 0);
  }
#pragma unroll
  for (int i = 0; i < 4; ++i) {
    int rowb = i0 + wm * 64 + i * 16 + quad * 4;
#pragma unroll
    for (int j = 0; j < 4; ++j) {
      int col = n0 + wn * 64 + j * 16 + lcol;
#pragma unroll
      for (int r = 0; r < 4; ++r)
        hidden[((size_t)(b * 1024 + rowb + r)) * 512 + col] = acc[i][j][r];
    }
  }
}

// ---------------- K2c: LayerNorm + mark softmax + hidden_n -> bf16 ---------
__global__ __launch_bounds__(256) void k2c_ln(const float* __restrict__ hidden,
    const float* __restrict__ ln_g, const float* __restrict__ ln_b,
    const float* __restrict__ w_pred, unsigned short* __restrict__ hn,
    float* __restrict__ out) {
  int row = blockIdx.x * 4 + (threadIdx.x >> 6);   // 4096 rows
  int l = threadIdx.x & 63;
  const float* hr = hidden + (size_t)row * 512 + 8 * l;
  float4 x0 = *(const float4*)hr;
  float4 x1 = *(const float4*)(hr + 4);
  float sm = x0.x + x0.y + x0.z + x0.w + x1.x + x1.y + x1.z + x1.w;
#pragma unroll
  for (int m = 1; m < 64; m <<= 1) sm += __shfl_xor(sm, m, 64);
  float mu = sm * (1.f / 512.f);
  float d[8] = {x0.x - mu, x0.y - mu, x0.z - mu, x0.w - mu,
                x1.x - mu, x1.y - mu, x1.z - mu, x1.w - mu};
  float vs = 0.f;
#pragma unroll
  for (int e = 0; e < 8; ++e) vs += d[e] * d[e];
#pragma unroll
  for (int m = 1; m < 64; m <<= 1) vs += __shfl_xor(vs, m, 64);
  float rs = rsqrtf(vs * (1.f / 512.f) + 1e-6f);
  float4 g0 = *(const float4*)(ln_g + 8 * l);
  float4 g1 = *(const float4*)(ln_g + 8 * l + 4);
  float4 b0 = *(const float4*)(ln_b + 8 * l);
  float4 b1 = *(const float4*)(ln_b + 8 * l + 4);
  float hnv[8];
  hnv[0] = d[0] * rs * g0.x + b0.x; hnv[1] = d[1] * rs * g0.y + b0.y;
  hnv[2] = d[2] * rs * g0.z + b0.z; hnv[3] = d[3] * rs * g0.w + b0.w;
  hnv[4] = d[4] * rs * g1.x + b1.x; hnv[5] = d[5] * rs * g1.y + b1.y;
  hnv[6] = d[6] * rs * g1.z + b1.z; hnv[7] = d[7] * rs * g1.w + b1.w;
  ushort4 u0, u1;
  u0.x = f2bf(hnv[0]); u0.y = f2bf(hnv[1]); u0.z = f2bf(hnv[2]); u0.w = f2bf(hnv[3]);
  u1.x = f2bf(hnv[4]); u1.y = f2bf(hnv[5]); u1.z = f2bf(hnv[6]); u1.w = f2bf(hnv[7]);
  *(ushort4*)(hn + (size_t)row * 512 + 8 * l) = u0;
  *(ushort4*)(hn + (size_t)row * 512 + 8 * l + 4) = u1;
  // mark logits
  float lg[20];
#pragma unroll
  for (int p = 0; p < 20; ++p) {
    const float* wp = w_pred + p * 512 + 8 * l;
    float4 w0 = *(const float4*)wp;
    float4 w1 = *(const float4*)(wp + 4);
    float v = hnv[0] * w0.x + hnv[1] * w0.y + hnv[2] * w0.z + hnv[3] * w0.w +
              hnv[4] * w1.x + hnv[5] * w1.y + hnv[6] * w1.z + hnv[7] * w1.w;
#pragma unroll
    for (int m = 1; m < 64; m <<= 1) v += __shfl_xor(v, m, 64);
    lg[p] = v;
  }
  if (l == 0) {
    float mx = -1e30f;
#pragma unroll
    for (int p = 0; p < 20; ++p) mx = fmaxf(mx, lg[p]);
    float e[20], sum = 0.f;
#pragma unroll
    for (int p = 0; p < 20; ++p) { e[p] = __expf(lg[p] - mx); sum += e[p]; }
    float inv = 1.f / sum;
    float* o = out + 4096 + (size_t)row * 20;
#pragma unroll
    for (int p = 0; p < 20; ++p) o[p] = e[p] * inv;
  }
}

// ---------------- K2d: cbuf = hidden_n @ w_in^T (bf16 MFMA) ----------------
__global__ __launch_bounds__(256) void k2d_cbuf(const unsigned short* __restrict__ hn,
    const float* __restrict__ w_in, float* __restrict__ cbuf) {
  __shared__ unsigned short As[128][32];
  __shared__ unsigned short Bs[128][32];
  int bid = blockIdx.x;          // 32mt * 4nt = 128
  int mt = bid >> 2, nt = bid & 3;
  int m0 = mt * 128, n0 = nt * 128;
  int tid = threadIdx.x;
  int lane = tid & 63, wv = tid >> 6;
  int wm = wv >> 1, wn = wv & 1;
  int quad = lane >> 4, lcol = lane & 15;
  f32x4 acc[4][4] = {};
  for (int kt = 0; kt < 512; kt += 32) {
    __syncthreads();
#pragma unroll
    for (int q = 0; q < 2; ++q) {
      int c = tid + 256 * q;
      int row = c >> 2, kq = (c & 3) << 3;
      *(uint4*)&As[row][kq] = *(const uint4*)(hn + (((size_t)(m0 + row)) << 9) + kt + kq);
    }
#pragma unroll
    for (int q = 0; q < 4; ++q) {
      int c = tid + 256 * q;
      int row = c >> 3, kq = (c & 7) << 2;
      float4 f = *(const float4*)(w_in + ((size_t)(n0 + row) << 9) + kt + kq);
      unsigned int p0 = pk_bf_trunc(f.x, f.y);
      unsigned int p1 = pk_bf_trunc(f.z, f.w);
      *(uint2*)&Bs[row][kq] = make_uint2(p0, p1);
    }
    __syncthreads();
    short8 af[4], bfr[4];
#pragma unroll
    for (int i = 0; i < 4; ++i)
      af[i] = *(const short8*)&As[wm * 64 + i * 16 + lcol][quad * 8];
#pragma unroll
    for (int j = 0; j < 4; ++j)
      bfr[j] = *(const short8*)&Bs[wn * 64 + j * 16 + lcol][quad * 8];
#pragma unroll
    for (int i = 0; i < 4; ++i)
#pragma unroll
      for (int j = 0; j < 4; ++j)
        acc[i][j] = __builtin_amdgcn_mfma_f32_16x16x32_bf16(af[i], bfr[j],
                                                            acc[i][j], 0, 0, 0);
  }
#pragma unroll
  for (int i = 0; i < 4; ++i) {
    int rowb = m0 + wm * 64 + i * 16 + quad * 4;
#pragma unroll
    for (int j = 0; j < 4; ++j) {
      int col = n0 + wn * 64 + j * 16 + lcol;
#pragma unroll
      for (int r = 0; r < 4; ++r)
        cbuf[((size_t)(rowb + r)) * 512 + col] = acc[i][j][r];
    }
  }
}

// ---------------- K4: bf16 MFMA GEMM h=relu(noise@w_noise^T + c) -----------
// BK=64, v_perm pack-convert; fused partial reduction over the 128-col slab.
__global__ __launch_bounds__(256) void k4_gemm(const float* __restrict__ noise,
    const unsigned short* __restrict__ wn_bf, const float* __restrict__ cbuf,
    const float* __restrict__ w_time, float* __restrict__ v_part) {
  __shared__ unsigned short As[128][64];
  __shared__ unsigned short Bs[128][64];
  __shared__ float v_s[128];
  int tid = threadIdx.x;
  int nt = blockIdx.x & 3;
  int mt = blockIdx.x >> 2;      // 1600 m-tiles
  size_t m0 = (size_t)mt * 128;
  int n0 = nt * 128;
  int lane = tid & 63, wv = tid >> 6;
  int wm = wv >> 1, wn = wv & 1;
  int quad = lane >> 4, lcol = lane & 15;
  f32x4 acc[4][4] = {};

  for (int kt = 0; kt < 512; kt += 64) {
    __syncthreads();
    // stage A: 128x64 fp32 -> bf16 (trunc pack, 1 v_perm per 2 elems)
#pragma unroll
    for (int q = 0; q < 8; ++q) {
      int c = tid + 256 * q;
      int row = c >> 4, kq = (c & 15) << 2;
      float4 f = *(const float4*)(noise + ((m0 + row) << 9) + kt + kq);
      unsigned int p0 = pk_bf_trunc(f.x, f.y);
      unsigned int p1 = pk_bf_trunc(f.z, f.w);
      *(uint2*)&As[row][kq] = make_uint2(p0, p1);
    }
    // stage B: 128x64 bf16 (pre-converted)
#pragma unroll
    for (int q = 0; q < 4; ++q) {
      int c = tid + 256 * q;
      int row = c >> 3, kq = (c & 7) << 3;
      *(uint4*)&Bs[row][kq] =
          *(const uint4*)(wn_bf + ((size_t)(n0 + row) << 9) + kt + kq);
    }
    __syncthreads();
#pragma unroll
    for (int kk = 0; kk < 64; kk += 32) {
      short8 af[4], bfr[4];
#pragma unroll
      for (int i = 0; i < 4; ++i)
        af[i] = *(const short8*)&As[wm * 64 + i * 16 + lcol][kk + quad * 8];
#pragma unroll
      for (int j = 0; j < 4; ++j)
        bfr[j] = *(const short8*)&Bs[wn * 64 + j * 16 + lcol][kk + quad * 8];
#pragma unroll
      for (int i = 0; i < 4; ++i)
#pragma unroll
        for (int j = 0; j < 4; ++j)
          acc[i][j] = __builtin_amdgcn_mfma_f32_16x16x32_bf16(af[i], bfr[j],
                                                              acc[i][j], 0, 0, 0);
    }
  }
  __syncthreads();
  if (tid < 128) v_s[tid] = 0.f;
  __syncthreads();
  float rowsum[4][4];
#pragma unroll
  for (int i = 0; i < 4; ++i)
#pragma unroll
    for (int r = 0; r < 4; ++r) rowsum[i][r] = 0.f;
#pragma unroll
  for (int i = 0; i < 4; ++i) {
    int rowb = wm * 64 + i * 16 + quad * 4;
#pragma unroll
    for (int j = 0; j < 4; ++j) {
      int col = n0 + wn * 64 + j * 16 + lcol;
      float wtv = w_time[col];
#pragma unroll
      for (int r = 0; r < 4; ++r) {
        int grow = (int)m0 + rowb + r;
        int bs = grow / NSAMP;
        float hval = acc[i][j][r] + cbuf[((size_t)bs << 9) + col];
        rowsum[i][r] += fmaxf(hval, 0.f) * wtv;
      }
    }
  }
#pragma unroll
  for (int i = 0; i < 4; ++i)
#pragma unroll
    for (int r = 0; r < 4; ++r) {
      float v = rowsum[i][r];
      v += __shfl_xor(v, 1, 64);
      v += __shfl_xor(v, 2, 64);
      v += __shfl_xor(v, 4, 64);
      v += __shfl_xor(v, 8, 64);
      if (lcol == 0) atomicAdd(&v_s[wm * 64 + i * 16 + quad * 4 + r], v);
    }
  __syncthreads();
  if (tid < 128) v_part[(size_t)nt * MTOT + m0 + tid] = v_s[tid];
}

// ---------------- K5: pred_time = mean_n softplus(sum of partials) ---------
__global__ __launch_bounds__(64) void k5_pred(const float* __restrict__ v_part,
                                              float* __restrict__ out) {
  int bs = blockIdx.x;
  int t = threadIdx.x;
  float sp = 0.f;
  if (t < NSAMP) {
    size_t idx = (size_t)bs * NSAMP + t;
    float v = v_part[idx] + v_part[(size_t)MTOT + idx] +
              v_part[2 * (size_t)MTOT + idx] + v_part[3 * (size_t)MTOT + idx];
    sp = softplusf(v);
  }
#pragma unroll
  for (int m = 1; m < 64; m <<= 1) sp += __shfl_xor(sp, m, 64);
  if (t == 0) out[bs] = sp * (1.f / NSAMP);
}

extern "C" void kernel_launch(void* const* d_in, const int* in_sizes, int n_in,
                              void* d_out, int out_size, void* d_ws, size_t ws_size,
                              hipStream_t stream) {
  const int* etype    = (const int*)d_in[0];
  const float* etime  = (const float*)d_in[1];
  const float* noise  = (const float*)d_in[2];
  const float* wt     = (const float*)d_in[3];
  const float* table  = (const float*)d_in[4];
  const float* w_sigma= (const float*)d_in[5];
  const float* w_gate = (const float*)d_in[6];
  const float* ln_g   = (const float*)d_in[7];
  const float* ln_b   = (const float*)d_in[8];
  const float* w_pred = (const float*)d_in[9];
  const float* w_in   = (const float*)d_in[10];
  const float* w_noise= (const float*)d_in[11];
  const float* w_time = (const float*)d_in[12];
  float* out = (float*)d_out;
  char* ws = (char*)d_ws;
  // workspace overlays by lifetime (21.56 MB total, under proven 21.7 MB):
  // R0 (8MB):  hv (k1-k1t) -> hidden (k2b-k2c) -> cbuf (k2d-k4)
  // R1 (8MB):  S_bf (k2a-k2b) -> v_part (k4-k5)
  // R2 (4MB):  hvT_bf (k1t-k2b) -> hidden_n (k2c-k2d)
  // R3: wn_bf 512KB ; R4: ab 64KB
  float* hv             = (float*)(ws);
  float* hidden         = (float*)(ws);
  float* cbuf           = (float*)(ws);
  unsigned short* S_bf  = (unsigned short*)(ws + 8388608);
  float* v_part         = (float*)(ws + 8388608);
  unsigned short* hvT   = (unsigned short*)(ws + 16777216);
  unsigned short* hn    = (unsigned short*)(ws + 16777216);
  unsigned short* wn_bf = (unsigned short*)(ws + 20971520);
  float* ab             = (float*)(ws + 21495808);

  hipLaunchKernelGGL(k0_prep, dim3(512), dim3(256), 0, stream, w_noise, wn_bf);
  hipLaunchKernelGGL(k1_embed, dim3(4096), dim3(256), 0, stream,
                     etype, etime, wt, table, w_sigma, w_gate, hv, ab);
  hipLaunchKernelGGL(k1t_transpose, dim3(512), dim3(256), 0, stream, hv, hvT);
  hipLaunchKernelGGL(k2a_scores, dim3(512), dim3(256), 0, stream, etime, ab, S_bf);
  hipLaunchKernelGGL(k2b_agg, dim3(128), dim3(256), 0, stream, S_bf, hvT, hidden);
  hipLaunchKernelGGL(k2c_ln, dim3(1024), dim3(256), 0, stream,
                     hidden, ln_g, ln_b, w_pred, hn, out);
  hipLaunchKernelGGL(k2d_cbuf, dim3(128), dim3(256), 0, stream, hn, w_in, cbuf);
  hipLaunchKernelGGL(k4_gemm, dim3(6400), dim3(256), 0, stream,
                     noise, wn_bf, cbuf, w_time, v_part);
  hipLaunchKernelGGL(k5_pred, dim3(4096), dim3(64), 0, stream, v_part, out);
}

// Round 3
// 795.514 us; speedup vs baseline: 1.4820x; 1.0528x over previous
//
#include <hip/hip_runtime.h>
#include <hip/hip_bf16.h>

typedef __attribute__((ext_vector_type(8))) short short8;
typedef __attribute__((ext_vector_type(4))) float f32x4;

#define NSAMP 50
#define MTOT 204800   // B*S*NS
#define BS_TOT 4096   // B*S

__device__ __forceinline__ unsigned short f2bf(float f) {
  unsigned int u = __builtin_bit_cast(unsigned int, f);
  u += 0x7fffu + ((u >> 16) & 1u);   // RNE
  return (unsigned short)(u >> 16);
}

// pack trunc(a),trunc(b) -> dword in ONE v_perm_b32 (bytes a2,a3,b2,b3)
__device__ __forceinline__ unsigned int pk_bf_trunc(float a, float b) {
  return __builtin_amdgcn_perm(__builtin_bit_cast(unsigned int, b),
                               __builtin_bit_cast(unsigned int, a), 0x07060302u);
}

__device__ __forceinline__ float softplusf(float x) {
  return fmaxf(x, 0.f) + log1pf(__expf(-fabsf(x)));
}

// ---------------- K0: w_noise -> bf16 --------------------------------------
__global__ __launch_bounds__(256) void k0_prep(const float* __restrict__ w_noise,
                                               unsigned short* __restrict__ wn_bf) {
  int r = blockIdx.x;            // 512 rows
  int t = threadIdx.x;
#pragma unroll
  for (int q = 0; q < 2; ++q) {
    int col = t + 256 * q;
    wn_bf[r * 512 + col] = f2bf(w_noise[r * 512 + col]);
  }
}

// ---------------- K1: embeddings + per-event dot products ------------------
__global__ __launch_bounds__(256) void k1_embed(const int* __restrict__ etype,
    const float* __restrict__ etime, const float* __restrict__ wt,
    const float* __restrict__ table, const float* __restrict__ w_sigma,
    const float* __restrict__ w_gate, float* __restrict__ hv,
    float* __restrict__ ab) {
  int bs = blockIdx.x;           // 4096
  int d = threadIdx.x;           // 256
  int s = bs & 1023;
  int ty = etype[bs];
  float te = table[ty * 256 + d];
  float t = etime[bs];
  int k = d & 127;
  float div_term = __expf((float)(2 * k) * (-9.210340371976184f / 256.f));
  float arg = (float)s * div_term + t * wt[k];
  float pe = (d < 128) ? sinf(arg) : cosf(arg);
  hv[(size_t)bs * 512 + d] = pe;
  hv[(size_t)bs * 512 + 256 + d] = te;
  float p0 = te * w_sigma[d];
  float p1 = te * w_sigma[256 + d];
  float p2 = te * w_gate[d];
  float p3 = te * w_gate[256 + d];
#pragma unroll
  for (int m = 1; m < 64; m <<= 1) {
    p0 += __shfl_xor(p0, m, 64);
    p1 += __shfl_xor(p1, m, 64);
    p2 += __shfl_xor(p2, m, 64);
    p3 += __shfl_xor(p3, m, 64);
  }
  __shared__ float red[4][4];
  if ((d & 63) == 0) {
    red[d >> 6][0] = p0; red[d >> 6][1] = p1;
    red[d >> 6][2] = p2; red[d >> 6][3] = p3;
  }
  __syncthreads();
  if (d < 4) ab[d * BS_TOT + bs] = red[0][d] + red[1][d] + red[2][d] + red[3][d];
}

// ---------------- K1t: hv[bs][512] -> hvT_bf[b][h][s] (bf16 transpose) -----
__global__ __launch_bounds__(256) void k1t_transpose(const float* __restrict__ hv,
                                                     unsigned short* __restrict__ hvT) {
  __shared__ float T[64][65];
  int bid = blockIdx.x;          // 4 * 16 * 8 = 512
  int b = bid >> 7;
  int st = (bid & 127) >> 3;
  int ht = bid & 7;
  int s0 = st * 64, h0 = ht * 64;
  int t = threadIdx.x;
#pragma unroll
  for (int q = 0; q < 16; ++q) {
    int idx = t + 256 * q;
    int r = idx >> 6, c = idx & 63;
    T[c][r] = hv[((size_t)(b * 1024 + s0 + r)) * 512 + h0 + c];
  }
  __syncthreads();
  int sq = t & 15;
#pragma unroll
  for (int q = 0; q < 4; ++q) {
    int hh = (t >> 4) + 16 * q;
    ushort4 u;
    u.x = f2bf(T[hh][sq * 4 + 0]);
    u.y = f2bf(T[hh][sq * 4 + 1]);
    u.z = f2bf(T[hh][sq * 4 + 2]);
    u.w = f2bf(T[hh][sq * 4 + 3]);
    *(ushort4*)(hvT + ((size_t)b << 19) + ((size_t)(h0 + hh) << 10) + s0 + sq * 4) = u;
  }
}

// ---------------- K2a: scores -> bf16 [b][i][j], zero for j>=i -------------
__global__ __launch_bounds__(256) void k2a_scores(const float* __restrict__ etime,
    const float* __restrict__ ab, unsigned short* __restrict__ S) {
  __shared__ float ti[8], bsi[8], bgi[8];
  int bid = blockIdx.x;          // 4 * 128 = 512
  int b = bid >> 7;
  int i0 = (bid & 127) * 8;
  int t = threadIdx.x;
  const float* et_b = etime + b * 1024;
  const float* as_b = ab + 0 * BS_TOT + b * 1024;
  const float* bs_b = ab + 1 * BS_TOT + b * 1024;
  const float* ag_b = ab + 2 * BS_TOT + b * 1024;
  const float* bg_b = ab + 3 * BS_TOT + b * 1024;
  if (t < 8) {
    ti[t] = et_b[i0 + t];
    bsi[t] = bs_b[i0 + t];
    bgi[t] = bg_b[i0 + t];
  }
  __syncthreads();
  unsigned short* Sb = S + ((size_t)b << 20);
  for (int j0 = 0; j0 < 1024; j0 += 256) {
    int j = j0 + t;
    float as_j = as_b[j], ag_j = ag_b[j], tj = et_b[j];
#pragma unroll
    for (int il = 0; il < 8; ++il) {
      int i = i0 + il;
      float sc = 0.f;
      if (j < i) {
        float sp = softplusf(as_j + bsi[il]);
        float g = 1.f / (1.f + __expf(-(ag_j + bgi[il])));
        sc = g * __expf(-sp * fabsf(tj - ti[il]));
      }
      Sb[((size_t)i << 10) + j] = f2bf(sc);
    }
  }
}

// ---------------- K2b: hidden = S @ hv  (bf16 MFMA, causal k-stop) ---------
// m-tile 64 -> grid 256 (full machine). [.][32] LDS = 64B stride, no conflicts.
__global__ __launch_bounds__(256) void k2b_agg(const unsigned short* __restrict__ S,
    const unsigned short* __restrict__ hvT, float* __restrict__ hidden) {
  __shared__ unsigned short As[64][32];
  __shared__ unsigned short Bs[128][32];
  int bid = blockIdx.x;          // 4b * 16mt * 4nt = 256
  int b = bid >> 6;
  int mt = (bid >> 2) & 15;
  int nt = bid & 3;
  int i0 = mt * 64, n0 = nt * 128;
  int kmax = i0 + 64;
  int tid = threadIdx.x;
  int lane = tid & 63, wv = tid >> 6;
  int wm = wv >> 1, wn = wv & 1;
  int quad = lane >> 4, lcol = lane & 15;
  const unsigned short* Sb = S + ((size_t)b << 20);
  const unsigned short* Hb = hvT + ((size_t)b << 19);
  f32x4 acc[2][4] = {};
  for (int kt = 0; kt < kmax; kt += 32) {
    __syncthreads();
    {
      int row = tid >> 2, kq = (tid & 3) << 3;
      *(uint4*)&As[row][kq] = *(const uint4*)(Sb + (((size_t)(i0 + row)) << 10) + kt + kq);
    }
#pragma unroll
    for (int q = 0; q < 2; ++q) {
      int c = tid + 256 * q;
      int row = c >> 2, kq = (c & 3) << 3;
      *(uint4*)&Bs[row][kq] = *(const uint4*)(Hb + (((size_t)(n0 + row)) << 10) + kt + kq);
    }
    __syncthreads();
    short8 af[2], bfr[4];
#pragma unroll
    for (int i = 0; i < 2; ++i)
      af[i] = *(const short8*)&As[wm * 32 + i * 16 + lcol][quad * 8];
#pragma unroll
    for (int j = 0; j < 4; ++j)
      bfr[j] = *(const short8*)&Bs[wn * 64 + j * 16 + lcol][quad * 8];
#pragma unroll
    for (int i = 0; i < 2; ++i)
#pragma unroll
      for (int j = 0; j < 4; ++j)
        acc[i][j] = __builtin_amdgcn_mfma_f32_16x16x32_bf16(af[i], bfr[j],
                                                            acc[i][j], 0, 0, 0);
  }
#pragma unroll
  for (int i = 0; i < 2; ++i) {
    int rowb = i0 + wm * 32 + i * 16 + quad * 4;
#pragma unroll
    for (int j = 0; j < 4; ++j) {
      int col = n0 + wn * 64 + j * 16 + lcol;
#pragma unroll
      for (int r = 0; r < 4; ++r)
        hidden[((size_t)(b * 1024 + rowb + r)) * 512 + col] = acc[i][j][r];
    }
  }
}

// ---------------- K2c: LayerNorm + mark softmax + hidden_n -> bf16 ---------
__global__ __launch_bounds__(256) void k2c_ln(const float* __restrict__ hidden,
    const float* __restrict__ ln_g, const float* __restrict__ ln_b,
    const float* __restrict__ w_pred, unsigned short* __restrict__ hn,
    float* __restrict__ out) {
  int row = blockIdx.x * 4 + (threadIdx.x >> 6);   // 4096 rows
  int l = threadIdx.x & 63;
  const float* hr = hidden + (size_t)row * 512 + 8 * l;
  float4 x0 = *(const float4*)hr;
  float4 x1 = *(const float4*)(hr + 4);
  float sm = x0.x + x0.y + x0.z + x0.w + x1.x + x1.y + x1.z + x1.w;
#pragma unroll
  for (int m = 1; m < 64; m <<= 1) sm += __shfl_xor(sm, m, 64);
  float mu = sm * (1.f / 512.f);
  float d[8] = {x0.x - mu, x0.y - mu, x0.z - mu, x0.w - mu,
                x1.x - mu, x1.y - mu, x1.z - mu, x1.w - mu};
  float vs = 0.f;
#pragma unroll
  for (int e = 0; e < 8; ++e) vs += d[e] * d[e];
#pragma unroll
  for (int m = 1; m < 64; m <<= 1) vs += __shfl_xor(vs, m, 64);
  float rs = rsqrtf(vs * (1.f / 512.f) + 1e-6f);
  float4 g0 = *(const float4*)(ln_g + 8 * l);
  float4 g1 = *(const float4*)(ln_g + 8 * l + 4);
  float4 b0 = *(const float4*)(ln_b + 8 * l);
  float4 b1 = *(const float4*)(ln_b + 8 * l + 4);
  float hnv[8];
  hnv[0] = d[0] * rs * g0.x + b0.x; hnv[1] = d[1] * rs * g0.y + b0.y;
  hnv[2] = d[2] * rs * g0.z + b0.z; hnv[3] = d[3] * rs * g0.w + b0.w;
  hnv[4] = d[4] * rs * g1.x + b1.x; hnv[5] = d[5] * rs * g1.y + b1.y;
  hnv[6] = d[6] * rs * g1.z + b1.z; hnv[7] = d[7] * rs * g1.w + b1.w;
  ushort4 u0, u1;
  u0.x = f2bf(hnv[0]); u0.y = f2bf(hnv[1]); u0.z = f2bf(hnv[2]); u0.w = f2bf(hnv[3]);
  u1.x = f2bf(hnv[4]); u1.y = f2bf(hnv[5]); u1.z = f2bf(hnv[6]); u1.w = f2bf(hnv[7]);
  *(ushort4*)(hn + (size_t)row * 512 + 8 * l) = u0;
  *(ushort4*)(hn + (size_t)row * 512 + 8 * l + 4) = u1;
  // mark logits
  float lg[20];
#pragma unroll
  for (int p = 0; p < 20; ++p) {
    const float* wp = w_pred + p * 512 + 8 * l;
    float4 w0 = *(const float4*)wp;
    float4 w1 = *(const float4*)(wp + 4);
    float v = hnv[0] * w0.x + hnv[1] * w0.y + hnv[2] * w0.z + hnv[3] * w0.w +
              hnv[4] * w1.x + hnv[5] * w1.y + hnv[6] * w1.z + hnv[7] * w1.w;
#pragma unroll
    for (int m = 1; m < 64; m <<= 1) v += __shfl_xor(v, m, 64);
    lg[p] = v;
  }
  if (l == 0) {
    float mx = -1e30f;
#pragma unroll
    for (int p = 0; p < 20; ++p) mx = fmaxf(mx, lg[p]);
    float e[20], sum = 0.f;
#pragma unroll
    for (int p = 0; p < 20; ++p) { e[p] = __expf(lg[p] - mx); sum += e[p]; }
    float inv = 1.f / sum;
    float* o = out + 4096 + (size_t)row * 20;
#pragma unroll
    for (int p = 0; p < 20; ++p) o[p] = e[p] * inv;
  }
}

// ---------------- K2d: cbuf = hidden_n @ w_in^T (bf16 MFMA, m-tile 64) -----
__global__ __launch_bounds__(256) void k2d_cbuf(const unsigned short* __restrict__ hn,
    const float* __restrict__ w_in, float* __restrict__ cbuf) {
  __shared__ unsigned short As[64][32];
  __shared__ unsigned short Bs[128][32];
  int bid = blockIdx.x;          // 64mt * 4nt = 256
  int mt = bid >> 2, nt = bid & 3;
  int m0 = mt * 64, n0 = nt * 128;
  int tid = threadIdx.x;
  int lane = tid & 63, wv = tid >> 6;
  int wm = wv >> 1, wn = wv & 1;
  int quad = lane >> 4, lcol = lane & 15;
  f32x4 acc[2][4] = {};
  for (int kt = 0; kt < 512; kt += 32) {
    __syncthreads();
    {
      int row = tid >> 2, kq = (tid & 3) << 3;
      *(uint4*)&As[row][kq] = *(const uint4*)(hn + (((size_t)(m0 + row)) << 9) + kt + kq);
    }
#pragma unroll
    for (int q = 0; q < 4; ++q) {
      int c = tid + 256 * q;
      int row = c >> 3, kq = (c & 7) << 2;
      float4 f = *(const float4*)(w_in + ((size_t)(n0 + row) << 9) + kt + kq);
      unsigned int p0 = pk_bf_trunc(f.x, f.y);
      unsigned int p1 = pk_bf_trunc(f.z, f.w);
      *(uint2*)&Bs[row][kq] = make_uint2(p0, p1);
    }
    __syncthreads();
    short8 af[2], bfr[4];
#pragma unroll
    for (int i = 0; i < 2; ++i)
      af[i] = *(const short8*)&As[wm * 32 + i * 16 + lcol][quad * 8];
#pragma unroll
    for (int j = 0; j < 4; ++j)
      bfr[j] = *(const short8*)&Bs[wn * 64 + j * 16 + lcol][quad * 8];
#pragma unroll
    for (int i = 0; i < 2; ++i)
#pragma unroll
      for (int j = 0; j < 4; ++j)
        acc[i][j] = __builtin_amdgcn_mfma_f32_16x16x32_bf16(af[i], bfr[j],
                                                            acc[i][j], 0, 0, 0);
  }
#pragma unroll
  for (int i = 0; i < 2; ++i) {
    int rowb = m0 + wm * 32 + i * 16 + quad * 4;
#pragma unroll
    for (int j = 0; j < 4; ++j) {
      int col = n0 + wn * 64 + j * 16 + lcol;
#pragma unroll
      for (int r = 0; r < 4; ++r)
        cbuf[((size_t)(rowb + r)) * 512 + col] = acc[i][j][r];
    }
  }
}

// ---------------- K4: bf16 MFMA GEMM h=relu(noise@w_noise^T + c) -----------
// BK=64; XOR-swizzled LDS (conflict-free at 128B row stride); XCD-aligned
// sibling swizzle so the 4 n-tiles of an m-tile share one XCD's L2.
__global__ __launch_bounds__(256) void k4_gemm(const float* __restrict__ noise,
    const unsigned short* __restrict__ wn_bf, const float* __restrict__ cbuf,
    const float* __restrict__ w_time, float* __restrict__ v_part) {
  __shared__ unsigned short As[128][64];
  __shared__ unsigned short Bs[128][64];
  __shared__ float v_s[128];
  int tid = threadIdx.x;
  // blockIdx = g*32 + r : mt = g*8 + (r&7), nt = r>>3  -> siblings differ by 8
  int gg = blockIdx.x >> 5, rr = blockIdx.x & 31;
  int nt = rr >> 3;
  int mt = (gg << 3) + (rr & 7);
  size_t m0 = (size_t)mt * 128;
  int n0 = nt * 128;
  int lane = tid & 63, wv = tid >> 6;
  int wm = wv >> 1, wn = wv & 1;
  int quad = lane >> 4, lcol = lane & 15;
  int m7 = lcol & 7;              // per-lane xor mask for fragment reads
  f32x4 acc[4][4] = {};

  for (int kt = 0; kt < 512; kt += 64) {
    __syncthreads();
    // stage A: 128x64 fp32 -> bf16 (trunc pack), swizzled granule
#pragma unroll
    for (int q = 0; q < 8; ++q) {
      int c = tid + 256 * q;
      int row = c >> 4, kq = (c & 15) << 2;
      float4 f = *(const float4*)(noise + ((m0 + row) << 9) + kt + kq);
      unsigned int p0 = pk_bf_trunc(f.x, f.y);
      unsigned int p1 = pk_bf_trunc(f.z, f.w);
      int pc = (((kq >> 3) ^ (row & 7)) << 3) | (kq & 7);
      *(uint2*)&As[row][pc] = make_uint2(p0, p1);
    }
    // stage B: 128x64 bf16 (pre-converted), swizzled granule
#pragma unroll
    for (int q = 0; q < 4; ++q) {
      int c = tid + 256 * q;
      int row = c >> 3, kq = (c & 7) << 3;
      int pc = ((c & 7) ^ (row & 7)) << 3;
      *(uint4*)&Bs[row][pc] =
          *(const uint4*)(wn_bf + ((size_t)(n0 + row) << 9) + kt + kq);
    }
    __syncthreads();
#pragma unroll
    for (int kk = 0; kk < 64; kk += 32) {
      int gq = quad + (kk >> 3);   // logical granule
      int pc = ((gq ^ m7) << 3);   // swizzled short-column
      short8 af[4], bfr[4];
#pragma unroll
      for (int i = 0; i < 4; ++i)
        af[i] = *(const short8*)&As[wm * 64 + i * 16 + lcol][pc];
#pragma unroll
      for (int j = 0; j < 4; ++j)
        bfr[j] = *(const short8*)&Bs[wn * 64 + j * 16 + lcol][pc];
#pragma unroll
      for (int i = 0; i < 4; ++i)
#pragma unroll
        for (int j = 0; j < 4; ++j)
          acc[i][j] = __builtin_amdgcn_mfma_f32_16x16x32_bf16(af[i], bfr[j],
                                                              acc[i][j], 0, 0, 0);
    }
  }
  __syncthreads();
  if (tid < 128) v_s[tid] = 0.f;
  __syncthreads();
  float rowsum[4][4];
#pragma unroll
  for (int i = 0; i < 4; ++i)
#pragma unroll
    for (int r = 0; r < 4; ++r) rowsum[i][r] = 0.f;
#pragma unroll
  for (int i = 0; i < 4; ++i) {
    int rowb = wm * 64 + i * 16 + quad * 4;
#pragma unroll
    for (int j = 0; j < 4; ++j) {
      int col = n0 + wn * 64 + j * 16 + lcol;
      float wtv = w_time[col];
#pragma unroll
      for (int r = 0; r < 4; ++r) {
        int grow = (int)m0 + rowb + r;
        int bs = grow / NSAMP;
        float hval = acc[i][j][r] + cbuf[((size_t)bs << 9) + col];
        rowsum[i][r] += fmaxf(hval, 0.f) * wtv;
      }
    }
  }
#pragma unroll
  for (int i = 0; i < 4; ++i)
#pragma unroll
    for (int r = 0; r < 4; ++r) {
      float v = rowsum[i][r];
      v += __shfl_xor(v, 1, 64);
      v += __shfl_xor(v, 2, 64);
      v += __shfl_xor(v, 4, 64);
      v += __shfl_xor(v, 8, 64);
      if (lcol == 0) atomicAdd(&v_s[wm * 64 + i * 16 + quad * 4 + r], v);
    }
  __syncthreads();
  if (tid < 128) v_part[(size_t)nt * MTOT + m0 + tid] = v_s[tid];
}

// ---------------- K5: pred_time = mean_n softplus(sum of partials) ---------
__global__ __launch_bounds__(64) void k5_pred(const float* __restrict__ v_part,
                                              float* __restrict__ out) {
  int bs = blockIdx.x;
  int t = threadIdx.x;
  float sp = 0.f;
  if (t < NSAMP) {
    size_t idx = (size_t)bs * NSAMP + t;
    float v = v_part[idx] + v_part[(size_t)MTOT + idx] +
              v_part[2 * (size_t)MTOT + idx] + v_part[3 * (size_t)MTOT + idx];
    sp = softplusf(v);
  }
#pragma unroll
  for (int m = 1; m < 64; m <<= 1) sp += __shfl_xor(sp, m, 64);
  if (t == 0) out[bs] = sp * (1.f / NSAMP);
}

extern "C" void kernel_launch(void* const* d_in, const int* in_sizes, int n_in,
                              void* d_out, int out_size, void* d_ws, size_t ws_size,
                              hipStream_t stream) {
  const int* etype    = (const int*)d_in[0];
  const float* etime  = (const float*)d_in[1];
  const float* noise  = (const float*)d_in[2];
  const float* wt     = (const float*)d_in[3];
  const float* table  = (const float*)d_in[4];
  const float* w_sigma= (const float*)d_in[5];
  const float* w_gate = (const float*)d_in[6];
  const float* ln_g   = (const float*)d_in[7];
  const float* ln_b   = (const float*)d_in[8];
  const float* w_pred = (const float*)d_in[9];
  const float* w_in   = (const float*)d_in[10];
  const float* w_noise= (const float*)d_in[11];
  const float* w_time = (const float*)d_in[12];
  float* out = (float*)d_out;
  char* ws = (char*)d_ws;
  // workspace overlays by lifetime (21.56 MB total):
  // R0 (8MB):  hv (k1-k1t) -> hidden (k2b-k2c) -> cbuf (k2d-k4)
  // R1 (8MB):  S_bf (k2a-k2b) -> v_part (k4-k5)
  // R2 (4MB):  hvT_bf (k1t-k2b) -> hidden_n (k2c-k2d)
  // R3: wn_bf 512KB ; R4: ab 64KB
  float* hv             = (float*)(ws);
  float* hidden         = (float*)(ws);
  float* cbuf           = (float*)(ws);
  unsigned short* S_bf  = (unsigned short*)(ws + 8388608);
  float* v_part         = (float*)(ws + 8388608);
  unsigned short* hvT   = (unsigned short*)(ws + 16777216);
  unsigned short* hn    = (unsigned short*)(ws + 16777216);
  unsigned short* wn_bf = (unsigned short*)(ws + 20971520);
  float* ab             = (float*)(ws + 21495808);

  hipLaunchKernelGGL(k0_prep, dim3(512), dim3(256), 0, stream, w_noise, wn_bf);
  hipLaunchKernelGGL(k1_embed, dim3(4096), dim3(256), 0, stream,
                     etype, etime, wt, table, w_sigma, w_gate, hv, ab);
  hipLaunchKernelGGL(k1t_transpose, dim3(512), dim3(256), 0, stream, hv, hvT);
  hipLaunchKernelGGL(k2a_scores, dim3(512), dim3(256), 0, stream, etime, ab, S_bf);
  hipLaunchKernelGGL(k2b_agg, dim3(256), dim3(256), 0, stream, S_bf, hvT, hidden);
  hipLaunchKernelGGL(k2c_ln, dim3(1024), dim3(256), 0, stream,
                     hidden, ln_g, ln_b, w_pred, hn, out);
  hipLaunchKernelGGL(k2d_cbuf, dim3(256), dim3(256), 0, stream, hn, w_in, cbuf);
  hipLaunchKernelGGL(k4_gemm, dim3(6400), dim3(256), 0, stream,
                     noise, wn_bf, cbuf, w_time, v_part);
  hipLaunchKernelGGL(k5_pred, dim3(4096), dim3(64), 0, stream, v_part, out);
}